// Round 6
// baseline (11.819 us; speedup 1.0000x reference)
//
#include <hip/hip_runtime.h>
#include <hip/hip_bf16.h>
#include <math.h>

// out[p][i][j] = sigmoid(C * D / 512), p<64, i,j<256
//   x[k] = polygons[p][k][1]*256 (compared against px=i)
//   y[k] = polygons[p][k][0]*256 (compared against py=j)
//
// Block = (p, 64-row stripe) -> 256 blocks x 256 threads. vs round 5 this
// dedupes the exact-IEEE mask divides 4x (they were replicated per 16-row
// stripe) and trims the phase-1 grid overlap (17x65 per 64 rows vs 4x(5x65)).
//
// Phase 1: cooperative S+ = sigmoid(+D/512) on a 4-px grid (17 x 65) -> LDS.
// Mask:    64-bit even-odd parity per (j, 64 rows), exact reference IEEE math
//          (same ops/order as the passing rounds 2-5).
// Phase 2: bilinear interp + conditional (1 - s). Zero transcendental ops.
//
// Floor model being tested: dur = F(~9us replay overhead) + ~2.6us HBM write.

#define LOAD_VERTS(poly_p)                                         \
    const float4* v4 = (const float4*)(poly_p);                    \
    float4 q0 = v4[0], q1 = v4[1], q2 = v4[2], q3 = v4[3];         \
    float x[8], y[8];                                              \
    y[0] = q0.x * 256.0f; x[0] = q0.y * 256.0f;                    \
    y[1] = q0.z * 256.0f; x[1] = q0.w * 256.0f;                    \
    y[2] = q1.x * 256.0f; x[2] = q1.y * 256.0f;                    \
    y[3] = q1.z * 256.0f; x[3] = q1.w * 256.0f;                    \
    y[4] = q2.x * 256.0f; x[4] = q2.y * 256.0f;                    \
    y[5] = q2.z * 256.0f; x[5] = q2.w * 256.0f;                    \
    y[6] = q3.x * 256.0f; x[6] = q3.y * 256.0f;                    \
    y[7] = q3.z * 256.0f; x[7] = q3.w * 256.0f;

__global__ __launch_bounds__(256)
void raster_fused(const float* __restrict__ poly, float* __restrict__ out) {
    __shared__ float Sg[17 * 65];  // S+ at rows i0+4*gr (gr=0..16), cols 4*gc

    int bid = blockIdx.x;
    int p  = bid >> 2;            // polygon
    int i0 = (bid & 3) << 6;      // stripe start row (0,64,128,192)
    int j  = threadIdx.x;         // column
    float py = (float)j;
    LOAD_VERTS(poly + (size_t)p * 16)

    // ---- phase 1: S+ = sigmoid(D/512) on the coarse grid (1105 pts) ----
    for (int q = threadIdx.x; q < 17 * 65; q += 256) {
        int gr = q / 65;
        int gc = q - gr * 65;
        float gi = (float)(i0 + (gr << 2));   // row coord (<=256, boundary virtual)
        float gj = (float)(gc << 2);          // col coord
        float s = 0.0f;
        #pragma unroll
        for (int k = 0; k < 8; ++k) {
            float dx = x[k] - gi;
            float dy = y[k] - gj;
            s += __builtin_amdgcn_sqrtf(fmaf(dx, dx, dy * dy));
        }
        float e = __expf(-s * (1.0f / 512.0f));
        Sg[q] = __builtin_amdgcn_rcpf(1.0f + e);
    }

    // ---- exact parity mask for rows [i0, i0+64) (IEEE, reference order) ----
    unsigned long long mask = 0ull;
    #pragma unroll
    for (int k = 0; k < 8; ++k) {
        int kn = (k + 1) & 7;
        bool cond = (y[k] > py) != (y[kn] > py);
        if (cond) {
            float denom = y[kn] - y[k];                                // nonzero when cond
            float xint  = (x[kn] - x[k]) * (py - y[k]) / denom + x[k]; // IEEE, ref order
            // m = #{ integer i in [0,256) : (float)i < xint }  (exact)
            int m;
            if (!(xint > 0.0f))       m = 0;
            else if (xint > 255.0f)   m = 256;
            else                      m = (int)ceilf(xint);
            int r = m - i0;          // rows i0..i0+r-1 of this stripe cross
            unsigned long long ones = (r <= 0) ? 0ull
                                    : (r >= 64) ? ~0ull
                                    : ((1ull << r) - 1ull);
            mask ^= ones;
        }
    }

    __syncthreads();

    // ---- phase 2: bilinear interp + sign flip; zero trans ops ----
    int   gc = j >> 2;
    float u  = (float)(j & 3) * 0.25f;

    // interpolate along u for the 17 grid rows this thread needs
    float A[17];
    #pragma unroll
    for (int gr = 0; gr < 17; ++gr) {
        float s0 = Sg[gr * 65 + gc];
        float s1 = Sg[gr * 65 + gc + 1];
        A[gr] = fmaf(u, s1 - s0, s0);
    }

    float* op = out + ((((size_t)p << 8) + i0) << 8) + j;
    #pragma unroll 8
    for (int r = 0; r < 64; ++r) {
        int   gr = r >> 2;
        float t  = (float)(r & 3) * 0.25f;
        float sp = fmaf(t, A[gr + 1] - A[gr], A[gr]);   // sigmoid(+D/512)
        float sv = ((mask >> r) & 1ull) ? sp : 1.0f - sp;
        op[(size_t)r << 8] = sv;
    }
}

extern "C" void kernel_launch(void* const* d_in, const int* in_sizes, int n_in,
                              void* d_out, int out_size, void* d_ws, size_t ws_size,
                              hipStream_t stream) {
    const float* poly = (const float*)d_in[0];
    float* out = (float*)d_out;
    // 64 polygons x 4 stripes = 256 blocks, 256 threads each
    raster_fused<<<256, 256, 0, stream>>>(poly, out);
}